// Round 5
// baseline (105.318 us; speedup 1.0000x reference)
//
#include <hip/hip_runtime.h>

typedef unsigned short u16;
typedef unsigned int u32;
typedef _Float16 half8 __attribute__((ext_vector_type(8)));   // MFMA A/B frag
typedef __fp16 fp16x2 __attribute__((ext_vector_type(2)));    // cvt_pkrtz result
typedef __attribute__((ext_vector_type(4))) float floatx4;    // MFMA acc

#define LSTRIDE 72   // u16 per LDS row: 72*2=144 B -> rows 16B-aligned

__device__ __forceinline__ u32 pkrtz(float lo, float hi) {
  fp16x2 h = __builtin_amdgcn_cvt_pkrtz(lo, hi);
  return __builtin_bit_cast(u32, h);
}

// ---------------------------------------------------------------------------
// out[bid][p*8+q][o] = S*acc - (1024*S+1)*csumB[o],  S = 2/255
//   acc = sum_m A[(sub,q)][m] * B[(p,o)][m]
//   A[(sub,q)][m] = fp16(1024 + w[q][m])  exact via 0x6400|v
//   B[(p,o)][m]   = fp16(Wpad[m-p][o])    Toeplitz shift baked at staging
// BM=128, BN=128, BK=64; 4 waves 2x2 of 64x64. Register-prefetch pipeline:
// chunk kc+1's global loads issue before chunk kc's MFMAs.
// ---------------------------------------------------------------------------
__global__ __launch_bounds__(256, 3) void byteformer_fused(
    const int* __restrict__ x, const float* __restrict__ Wm,
    float* __restrict__ out) {
  __shared__ __align__(16) u16 As[128 * LSTRIDE];
  __shared__ __align__(16) u16 Bs[128 * LSTRIDE];
  __shared__ float part[256];
  __shared__ float csum[64];

  const int t = threadIdx.x;
  const int mtile = blockIdx.x;        // 0..127 (16 sub-blocks each)
  const int n0 = blockIdx.y * 128;
  const int p0 = 2 * blockIdx.y;

  const int wave = t >> 6, lane = t & 63;
  const int wm = wave >> 1, wn = wave & 1;
  const int quad = lane >> 4, l16 = lane & 15;

  // A staging: thread -> (sub, k-group, q-half)
  const int sA_sub = t >> 4;
  const int sA_kg  = (t >> 1) & 7;
  const int sA_qh  = t & 1;
  const long xrow = ((long)mtile * 16 + sA_sub) * 512;
  const int sB_o = lane;               // wave-coalesced W reads

  floatx4 acc[4][4];
  #pragma unroll
  for (int mt = 0; mt < 4; ++mt)
    #pragma unroll
    for (int nt = 0; nt < 4; ++nt)
      acc[mt][nt] = floatx4{0.f, 0.f, 0.f, 0.f};

  float csum_local = 0.0f;

  int4 a0, a1; int c8; float f[17];

  auto loadG = [&](int kc, int4& A0, int4& A1, int& C8, float (&F)[17]) {
    const int base = kc * 64 + sA_kg * 8;
    A0 = *(const int4*)&x[xrow + base];
    A1 = *(const int4*)&x[xrow + base + 4];
    C8 = (base + 8 < 512) ? x[xrow + base + 8] : 0;   // sub-block zero pad
    const int cb = kc * 64 + 16 * wave - p0 - 1;
    #pragma unroll
    for (int j = 0; j < 17; ++j) {
      int c = cb + j;                                  // wave-uniform
      F[j] = (c >= 0 && c < 496) ? Wm[c * 64 + sB_o] : 0.0f;
    }
  };

  auto writeLDS = [&]() {
    // ---- A: bytes -> 8-bit windows -> fp16(1024+v), one uint4 store per q
    int c[9] = {a0.x, a0.y, a0.z, a0.w, a1.x, a1.y, a1.z, a1.w, c8};
    u32 w16[8];
    #pragma unroll
    for (int j = 0; j < 8; ++j) w16[j] = ((u32)c[j] << 8) | (u32)c[j + 1];
    #pragma unroll
    for (int qi = 0; qi < 4; ++qi) {
      const int q = sA_qh * 4 + qi;
      const int sh = 8 - q;
      u32 d[4];
      #pragma unroll
      for (int jp = 0; jp < 4; ++jp) {
        u32 v0 = (w16[2 * jp] >> sh) & 255u;
        u32 v1 = (w16[2 * jp + 1] >> sh) & 255u;
        d[jp] = v0 | (v1 << 16) | 0x64006400u;
      }
      *(uint4*)&As[(sA_sub * 8 + q) * LSTRIDE + sA_kg * 8] =
          uint4{d[0], d[1], d[2], d[3]};
    }
    // ---- B: pkrtz pair-packs, two shifted rows (pp=0/1) per m-group
    u32 pe[8], po[8];
    #pragma unroll
    for (int i = 0; i < 8; ++i) {
      pe[i] = pkrtz(f[2 * i], f[2 * i + 1]);
      po[i] = pkrtz(f[2 * i + 1], f[2 * i + 2]);
    }
    #pragma unroll
    for (int g = 0; g < 2; ++g) {
      const int mgrp = 2 * wave + g;
      *(uint4*)&Bs[(0 * 64 + sB_o) * LSTRIDE + mgrp * 8] =
          uint4{po[g * 4], po[g * 4 + 1], po[g * 4 + 2], po[g * 4 + 3]};
      *(uint4*)&Bs[(1 * 64 + sB_o) * LSTRIDE + mgrp * 8] =
          uint4{pe[g * 4], pe[g * 4 + 1], pe[g * 4 + 2], pe[g * 4 + 3]};
    }
    #pragma unroll
    for (int j = 1; j <= 16; ++j) csum_local += f[j];
  };

  loadG(0, a0, a1, c8, f);
  writeLDS();
  __syncthreads();

  for (int kc = 0; kc < 8; ++kc) {
    int4 na0, na1; int nc8; float nf[17];
    if (kc < 7) loadG(kc + 1, na0, na1, nc8, nf);   // prefetch: in flight over MFMAs

    #pragma unroll
    for (int ks = 0; ks < 2; ++ks) {
      const int koff = ks * 32 + quad * 8;
      half8 af[4], bf[4];
      #pragma unroll
      for (int mt = 0; mt < 4; ++mt)
        af[mt] = *(const half8*)&As[(wm * 64 + mt * 16 + l16) * LSTRIDE + koff];
      #pragma unroll
      for (int nt = 0; nt < 4; ++nt)
        bf[nt] = *(const half8*)&Bs[(wn * 64 + nt * 16 + l16) * LSTRIDE + koff];
      #pragma unroll
      for (int mt = 0; mt < 4; ++mt)
        #pragma unroll
        for (int nt = 0; nt < 4; ++nt)
          acc[mt][nt] = __builtin_amdgcn_mfma_f32_16x16x32_f16(
              af[mt], bf[nt], acc[mt][nt], 0, 0, 0);
    }
    __syncthreads();                   // all LDS reads of chunk kc done
    if (kc < 7) {
      a0 = na0; a1 = na1; c8 = nc8;
      #pragma unroll
      for (int j = 0; j < 17; ++j) f[j] = nf[j];
      writeLDS();
      __syncthreads();                 // writes visible
    }
  }

  // ---- csumB reduction
  part[t] = csum_local;
  __syncthreads();
  if (t < 64)
    csum[t] = part[t] + part[t + 64] + part[t + 128] + part[t + 192];
  __syncthreads();

  // ---- epilogue: C/D col=l16, row=quad*4+reg. Row-grouped store order:
  // the 4 nt stores of one output row are back-to-back -> full-line writes.
  const float S = 2.0f / 255.0f;
  const float K1 = 1024.0f * S + 1.0f;
  const int p = p0 + wn;               // p is wave-uniform here
  float cs[4];
  #pragma unroll
  for (int nt = 0; nt < 4; ++nt) cs[nt] = K1 * csum[nt * 16 + l16];
  #pragma unroll
  for (int mt = 0; mt < 4; ++mt) {
    int mbase = mtile * 128 + wm * 64 + mt * 16 + quad * 4;
    #pragma unroll
    for (int i = 0; i < 4; ++i) {
      int mr = mbase + i;
      int bid = mr >> 3, q = mr & 7;
      float* orow = out + (long)bid * 8192 + (p * 8 + q) * 64;
      #pragma unroll
      for (int nt = 0; nt < 4; ++nt)
        orow[nt * 16 + l16] = S * acc[mt][nt][i] - cs[nt];
    }
  }
}

extern "C" void kernel_launch(void* const* d_in, const int* in_sizes, int n_in,
                              void* d_out, int out_size, void* d_ws, size_t ws_size,
                              hipStream_t stream) {
  const int* x = (const int*)d_in[0];        // (256, 4096) byte values as int32
  const float* Wm = (const float*)d_in[1];   // (496, 64) fp32
  float* out = (float*)d_out;                // (256, 8, 128, 64) fp32
  byteformer_fused<<<dim3(128, 8), dim3(256), 0, stream>>>(x, Wm, out);
}